// Round 8
// baseline (7700.824 us; speedup 1.0000x reference)
//
#include <hip/hip_runtime.h>

// ============================================================================
// 2-layer tanh RNN, B=32, S=2048, D=H=O=512.
//  r7: latency-first phase schedule on top of r6's self-tagged rings.
//      Each phase: [poll h0(p-1) -> GEMM0 -> sync1 -> store h0(p) EARLY]
//      then the L1 shadow [issue h1 poll || GEMM1 -> check -> GEMM2 -> sync2
//      -> store h1(p-1)+dout, prefetch z0(p+1)]. The critical h0 store now
//      propagates through MALL while the WG does L1 work, overlapping the
//      store-visibility + detect latency that previously serialized.
//      Tags/epochs/ring depth identical to r6 (proven). Polls keep retry caps.
// ============================================================================

typedef short v8s __attribute__((ext_vector_type(8)));
typedef int   v4i __attribute__((ext_vector_type(4)));
typedef float v4f __attribute__((ext_vector_type(4)));

#define B_  32
#define S_  2048
#define DH  512
#define SLOT32 16384                      // u32 per ring slot (32 x 512)

// ws layout (bytes)
#define BIAS_OFF  0                       // [2][512] f32 (b_ih + b_hh)
#define H0_OFF    8192                    // 4 slots x 64KB packed u32
#define H1_OFF    (H0_OFF + 4 * 65536)
#define WOUT_OFF  (H1_OFF + 4 * 65536)    // w_out bf16 [512][512]
#define WIH0_OFF  (WOUT_OFF + 524288)     // w_ih[0] bf16 [512][512]

#define PARTA_BYTES (8 * 4 * 64 * 16)     // 32KB  GEMM0 partials
#define PARTB_BYTES (8 * 2 * 4 * 64 * 16) // 64KB  GEMM1/2 partials
#define LDS_BYTES   (PARTA_BYTES + PARTB_BYTES)

static __device__ __forceinline__ unsigned short f2bf(float f) {  // RNE
  unsigned int u = __builtin_bit_cast(unsigned int, f);
  u += 0x7fffu + ((u >> 16) & 1u);
  return (unsigned short)(u >> 16);
}
static __device__ __forceinline__ float bf2f(unsigned short h) {
  return __builtin_bit_cast(float, ((unsigned int)h) << 16);
}
static __device__ __forceinline__ unsigned packh(float f, unsigned ep) {
  unsigned short hv = f2bf(f);
  unsigned short lv = f2bf(f - bf2f(hv));
  return ((unsigned)hv << 16) | ((unsigned)lv & 0xFFF8u) | ep;
}
static __device__ __forceinline__ v8s pack8(float4 f0, float4 f1) {
  v8s r;
  r[0] = (short)f2bf(f0.x); r[1] = (short)f2bf(f0.y);
  r[2] = (short)f2bf(f0.z); r[3] = (short)f2bf(f0.w);
  r[4] = (short)f2bf(f1.x); r[5] = (short)f2bf(f1.y);
  r[6] = (short)f2bf(f1.z); r[7] = (short)f2bf(f1.w);
  return r;
}
static __device__ __forceinline__ float fast_tanh(float v) {
  float c = fminf(15.f, fmaxf(-15.f, v));
  float e = __expf(2.f * c);
  return (e - 1.f) * __builtin_amdgcn_rcpf(e + 1.f);
}

// ---- device-scope (MALL) accessors ----------------------------------------
static __device__ __forceinline__ v4i ld16v(const unsigned* p) {
  v4i r;
  asm volatile("global_load_dwordx4 %0, %1, off sc1"
               : "=v"(r) : "v"(p) : "memory");
  return r;
}
static __device__ __forceinline__ float ld4(const void* p) {  // cached
  float r;
  asm volatile("global_load_dword %0, %1, off"
               : "=v"(r) : "v"(p) : "memory");
  return r;
}
static __device__ __forceinline__ void st32u(void* p, unsigned v) {
  asm volatile("global_store_dword %0, %1, off sc1"
               :: "v"(p), "v"(v) : "memory");
}
#define WAITN0() do { asm volatile("s_waitcnt vmcnt(0)" ::: "memory"); \
    __builtin_amdgcn_sched_barrier(0); } while (0)

// Poll one matrix fragment set (16 u32/lane).
static __device__ __forceinline__ void poll_frag(const unsigned* b, unsigned ep,
                                                 bool* bad, v4i* o0, v4i* o1,
                                                 v4i* o2, v4i* o3) {
  v4i a0, a1, a2, a3;
  int t = 0;
  for (;;) {
    a0 = ld16v(b); a1 = ld16v(b + 4); a2 = ld16v(b + 32); a3 = ld16v(b + 36);
    WAITN0();
    if (*bad) break;
    unsigned d = 0;
    #pragma unroll
    for (int j = 0; j < 4; ++j)
      d |= ((unsigned)a0[j] ^ ep) | ((unsigned)a1[j] ^ ep)
         | ((unsigned)a2[j] ^ ep) | ((unsigned)a3[j] ^ ep);
    if (__all((d & 7u) == 0u)) break;
    if (++t > (1 << 15)) { *bad = true; break; }
  }
  *o0 = a0; *o1 = a1; *o2 = a2; *o3 = a3;
}
static __device__ __forceinline__ void unp(v4i a, v4i b, v8s* hi, v8s* lo) {
  v8s h, l;
  #pragma unroll
  for (int j = 0; j < 4; ++j) {
    unsigned ua = (unsigned)a[j], ub = (unsigned)b[j];
    h[j]     = (short)(ua >> 16);   l[j]     = (short)(ua & 0xFFF8u);
    h[4 + j] = (short)(ub >> 16);   l[4 + j] = (short)(ub & 0xFFF8u);
  }
  *hi = h; *lo = l;
}

// ---------------------------------------------------------------------------
__global__ void rnn_init(const float* __restrict__ hidden,
                         const float* __restrict__ b_ih,
                         const float* __restrict__ b_hh,
                         const float* __restrict__ w_out,
                         const float* __restrict__ w_ih,
                         float* __restrict__ bias,
                         unsigned* __restrict__ h0ring,
                         unsigned* __restrict__ h1ring,
                         unsigned short* __restrict__ woutbf,
                         unsigned short* __restrict__ wih0bf) {
  int i = blockIdx.x * blockDim.x + threadIdx.x;
  int nth = gridDim.x * blockDim.x;
  for (int t = i; t < 1024; t += nth) bias[t] = b_ih[t] + b_hh[t];
  for (int t = i; t < 2 * B_ * DH; t += nth) {     // initial h -> slot 3, tag 7
    int l = t >> 14;
    int off = t & 16383;
    unsigned* ring = l ? h1ring : h0ring;
    ring[3 * SLOT32 + off] = packh(hidden[t], 7u);
  }
  for (int t = i; t < 512 * 512; t += nth) {
    woutbf[t] = f2bf(w_out[t]);
    wih0bf[t] = f2bf(w_ih[t]);
  }
}

// ---------------------------------------------------------------------------
// Bulk projection: dst[r][:] = src[r][:] @ wb^T + bias (64 rows/WG, in-place ok)
__global__ __launch_bounds__(512) void proj64(
    const float* __restrict__ src,
    float* __restrict__ dst,
    const unsigned short* __restrict__ wb,
    const float* __restrict__ bias) {
  __shared__ unsigned short lds[64 * 512];
  const int tid = threadIdx.x;
  const int wid = tid >> 6;
  const int lane = tid & 63;
  const size_t row0 = (size_t)blockIdx.x * 64;

  #pragma unroll
  for (int it = 0; it < 8; ++it) {
    int c = it * 512 + tid;
    int row = c >> 6;
    int col8 = c & 63;
    const float4* s4 = (const float4*)(src + (row0 + row) * DH + col8 * 8);
    float4 f0 = s4[0], f1 = s4[1];
    v8s t = pack8(f0, f1);
    int byteoff = row * 1024 + ((col8 * 16) ^ ((row & 7) << 4));
    *(v8s*)((char*)lds + byteoff) = t;
  }
  __syncthreads();

  const int l15 = lane & 15;
  const int kq = (lane >> 4) * 8;

  for (int nt = wid; nt < 32; nt += 8) {
    v4f acc[4];
    #pragma unroll
    for (int mt = 0; mt < 4; ++mt) acc[mt] = (v4f){0.f, 0.f, 0.f, 0.f};
    const unsigned short* wr = wb + (size_t)(nt * 16 + l15) * 512;
    #pragma unroll
    for (int ks = 0; ks < 16; ++ks) {
      int kk = ks * 32 + kq;
      v8s bfrag = *(const v8s*)(wr + kk);
      #pragma unroll
      for (int mt = 0; mt < 4; ++mt) {
        int row = mt * 16 + l15;
        int byteoff = row * 1024 + ((kk * 2) ^ ((row & 7) << 4));
        v8s afrag = *(const v8s*)((char*)lds + byteoff);
        acc[mt] = __builtin_amdgcn_mfma_f32_16x16x32_bf16(afrag, bfrag, acc[mt], 0, 0, 0);
      }
    }
    float bo = bias[nt * 16 + l15];
    #pragma unroll
    for (int mt = 0; mt < 4; ++mt)
      #pragma unroll
      for (int r = 0; r < 4; ++r) {
        int row = mt * 16 + (lane >> 4) * 4 + r;
        int col = nt * 16 + l15;
        dst[(row0 + row) * DH + col] = acc[mt][r] + bo;
      }
  }
}

// ---------------------------------------------------------------------------
// Fused persistent kernel. wg = mh*8 + fs. 8 waves = 8 K-eighths.
// Phase p: [poll h0(p-1) -> GEMM0 -> sync1 -> finishers store h0(p)]
//          [h1 poll || GEMM1 -> GEMM2 -> sync2 -> finishers store h1(p-1)].
__global__ __launch_bounds__(512) void rnn_fused(
    const float* __restrict__ z0,     // d_out: Z0 (overwritten by dout)
    const float* __restrict__ w_ih,
    const float* __restrict__ w_hh,
    const float* __restrict__ bias,
    unsigned* __restrict__ h0ring,
    unsigned* __restrict__ h1ring,
    float* __restrict__ dout) {
  extern __shared__ char smem[];
  v4f* partA = (v4f*)smem;                            // [8][4][64]
  v4f* partB = (v4f*)(smem + PARTA_BYTES);            // [8][2][4][64]

  const int wg = blockIdx.x;
  const int mh = wg >> 3;               // batch half
  const int fs = wg & 7;                // feature slice (64 feats)

  const int tid = threadIdx.x;
  const int wid = tid >> 6;             // K-eighth
  const int lane = tid & 63;
  const int l15 = lane & 15;
  const int kq = (lane >> 4) * 8;
  const int q4 = (lane >> 4) * 4;

  // resident weights: wfrag[g][n][ks], g: {w_hh0, w_ih1, w_hh1}
  v8s wfrag[3][4][2];
  {
    const float* wsrcs[3] = { w_hh, w_ih + 512 * 512, w_hh + 512 * 512 };
    #pragma unroll
    for (int g = 0; g < 3; ++g)
      #pragma unroll
      for (int n = 0; n < 4; ++n)
        #pragma unroll
        for (int ks = 0; ks < 2; ++ks) {
          const float* srow = wsrcs[g] +
              (size_t)(fs * 64 + n * 16 + l15) * 512 + wid * 64 + ks * 32 + kq;
          wfrag[g][n][ks] = pack8(*(const float4*)srow, *(const float4*)(srow + 4));
        }
  }
  const int nf = wid & 3;               // finisher n-tile (wid<4)
  const float bias1v = bias[512 + fs * 64 + nf * 16 + l15];
  const size_t abase = (size_t)(mh * 16 + l15) * 512 + wid * 64 + kq;
  const int featf = fs * 64 + nf * 16 + l15;

  bool bad = false;

  // prologue: z0(0) prefetch (finishers)
  float zp[4] = {0.f, 0.f, 0.f, 0.f};
  if (wid < 4) {
    #pragma unroll
    for (int r = 0; r < 4; ++r)
      zp[r] = ld4(z0 + ((size_t)(mh * 16 + q4 + r) * S_ + 0) * DH + featf);
  }

  for (int p = 0; p <= S_; ++p) {
    // ======== L0-critical sub-phase =======================================
    const unsigned ep0 = (p == 0) ? 7u : (unsigned)(((p - 1) >> 2) & 7);
    const unsigned* h0b = h0ring + (size_t)((p + 3) & 3) * SLOT32 + abase;
    v4i A0, A1, A2, A3;
    poll_frag(h0b, ep0, &bad, &A0, &A1, &A2, &A3);   // drains zp prefetch too
    v8s h0h0, h0l0, h0h1, h0l1;
    unp(A0, A1, &h0h0, &h0l0);
    unp(A2, A3, &h0h1, &h0l1);

    v4f acc0[4];
    #pragma unroll
    for (int n = 0; n < 4; ++n) {
      acc0[n] = (v4f){0.f, 0.f, 0.f, 0.f};
      acc0[n] = __builtin_amdgcn_mfma_f32_16x16x32_bf16(h0h0, wfrag[0][n][0], acc0[n], 0, 0, 0);
      acc0[n] = __builtin_amdgcn_mfma_f32_16x16x32_bf16(h0l0, wfrag[0][n][0], acc0[n], 0, 0, 0);
      acc0[n] = __builtin_amdgcn_mfma_f32_16x16x32_bf16(h0h1, wfrag[0][n][1], acc0[n], 0, 0, 0);
      acc0[n] = __builtin_amdgcn_mfma_f32_16x16x32_bf16(h0l1, wfrag[0][n][1], acc0[n], 0, 0, 0);
      partA[(wid * 4 + n) * 64 + lane] = acc0[n];
    }
    __syncthreads();                                  // sync1

    if (wid < 4 && p < S_) {                          // EARLY h0(p) store
      v4f s0 = {0.f, 0.f, 0.f, 0.f};
      #pragma unroll
      for (int w = 0; w < 8; ++w) s0 += partA[(w * 4 + nf) * 64 + lane];
      const unsigned ep = (unsigned)((p >> 2) & 7);
      unsigned* dst = h0ring + (size_t)(p & 3) * SLOT32;
      #pragma unroll
      for (int r = 0; r < 4; ++r) {
        float h0v = fast_tanh(zp[r] + s0[r]);
        st32u(dst + (size_t)(mh * 16 + q4 + r) * 512 + featf, packh(h0v, ep));
      }
    }

    // ======== L1 shadow sub-phase =========================================
    v4i B0, B1, B2, B3;
    const unsigned ep1 = (p == 1) ? 7u : (unsigned)(((p - 2) >> 2) & 7);
    const unsigned* h1b = h1ring + (size_t)((p + 2) & 3) * SLOT32 + abase;
    if (p >= 1) {                                     // issue h1 loads early
      B0 = ld16v(h1b); B1 = ld16v(h1b + 4);
      B2 = ld16v(h1b + 32); B3 = ld16v(h1b + 36);
    }

    v4f acc1[4], acc2[4];
    #pragma unroll
    for (int n = 0; n < 4; ++n) {                     // GEMM1 under h1 flight
      acc1[n] = (v4f){0.f, 0.f, 0.f, 0.f};
      acc2[n] = (v4f){0.f, 0.f, 0.f, 0.f};
      acc1[n] = __builtin_amdgcn_mfma_f32_16x16x32_bf16(h0h0, wfrag[1][n][0], acc1[n], 0, 0, 0);
      acc1[n] = __builtin_amdgcn_mfma_f32_16x16x32_bf16(h0l0, wfrag[1][n][0], acc1[n], 0, 0, 0);
      acc1[n] = __builtin_amdgcn_mfma_f32_16x16x32_bf16(h0h1, wfrag[1][n][1], acc1[n], 0, 0, 0);
      acc1[n] = __builtin_amdgcn_mfma_f32_16x16x32_bf16(h0l1, wfrag[1][n][1], acc1[n], 0, 0, 0);
    }

    if (p >= 1) {
      WAITN0();
      unsigned d = 0;
      #pragma unroll
      for (int j = 0; j < 4; ++j)
        d |= ((unsigned)B0[j] ^ ep1) | ((unsigned)B1[j] ^ ep1)
           | ((unsigned)B2[j] ^ ep1) | ((unsigned)B3[j] ^ ep1);
      if (!__all((d & 7u) == 0u))
        poll_frag(h1b, ep1, &bad, &B0, &B1, &B2, &B3);
      v8s h1h0, h1l0, h1h1, h1l1;
      unp(B0, B1, &h1h0, &h1l0);
      unp(B2, B3, &h1h1, &h1l1);
      #pragma unroll
      for (int n = 0; n < 4; ++n) {
        acc2[n] = __builtin_amdgcn_mfma_f32_16x16x32_bf16(h1h0, wfrag[2][n][0], acc2[n], 0, 0, 0);
        acc2[n] = __builtin_amdgcn_mfma_f32_16x16x32_bf16(h1l0, wfrag[2][n][0], acc2[n], 0, 0, 0);
        acc2[n] = __builtin_amdgcn_mfma_f32_16x16x32_bf16(h1h1, wfrag[2][n][1], acc2[n], 0, 0, 0);
        acc2[n] = __builtin_amdgcn_mfma_f32_16x16x32_bf16(h1l1, wfrag[2][n][1], acc2[n], 0, 0, 0);
      }
    }
    #pragma unroll
    for (int n = 0; n < 4; ++n) {
      partB[((wid * 2 + 0) * 4 + n) * 64 + lane] = acc1[n];
      partB[((wid * 2 + 1) * 4 + n) * 64 + lane] = acc2[n];
    }
    __syncthreads();                                  // sync2

    if (wid < 4) {
      if (p >= 1) {                                   // h1(p-1) finish
        v4f s1 = {0.f, 0.f, 0.f, 0.f}, s2 = {0.f, 0.f, 0.f, 0.f};
        #pragma unroll
        for (int w = 0; w < 8; ++w) {
          s1 += partB[((w * 2 + 0) * 4 + nf) * 64 + lane];
          s2 += partB[((w * 2 + 1) * 4 + nf) * 64 + lane];
        }
        const unsigned ep = (unsigned)(((p - 1) >> 2) & 7);
        unsigned* dst = h1ring + (size_t)((p - 1) & 3) * SLOT32;
        #pragma unroll
        for (int r = 0; r < 4; ++r) {
          float h1v = fast_tanh(s1[r] + s2[r] + bias1v);
          st32u(dst + (size_t)(mh * 16 + q4 + r) * 512 + featf, packh(h1v, ep));
          dout[((size_t)(mh * 16 + q4 + r) * S_ + (p - 1)) * DH + featf] = h1v;
        }
      }
      if (p + 1 <= S_) {                              // prefetch z0(p+1)
        const int pz = (p + 1 < S_) ? (p + 1) : (S_ - 1);
        #pragma unroll
        for (int r = 0; r < 4; ++r)
          zp[r] = ld4(z0 + ((size_t)(mh * 16 + q4 + r) * S_ + pz) * DH + featf);
      }
    }
  }
}

// ---------------------------------------------------------------------------
extern "C" void kernel_launch(void* const* d_in, const int* in_sizes, int n_in,
                              void* d_out, int out_size, void* d_ws, size_t ws_size,
                              hipStream_t stream) {
  const float* x      = (const float*)d_in[0];
  const float* hidden = (const float*)d_in[1];
  const float* w_ih   = (const float*)d_in[2];
  const float* w_hh   = (const float*)d_in[3];
  const float* b_ih   = (const float*)d_in[4];
  const float* b_hh   = (const float*)d_in[5];
  const float* w_out  = (const float*)d_in[6];
  const float* b_out  = (const float*)d_in[7];
  float* out = (float*)d_out;

  char* wsb = (char*)d_ws;
  float* bias            = (float*)(wsb + BIAS_OFF);
  unsigned* h0ring       = (unsigned*)(wsb + H0_OFF);
  unsigned* h1ring       = (unsigned*)(wsb + H1_OFF);
  unsigned short* woutbf = (unsigned short*)(wsb + WOUT_OFF);
  unsigned short* wih0bf = (unsigned short*)(wsb + WIH0_OFF);

  rnn_init<<<256, 256, 0, stream>>>(hidden, b_ih, b_hh, w_out, w_ih,
                                    bias, h0ring, h1ring, woutbf, wih0bf);
  // Z0 = x @ w_ih0^T + (b_ih0 + b_hh0) -> d_out
  proj64<<<(B_ * S_) / 64, 512, 0, stream>>>(x, out, wih0bf, bias);
  rnn_fused<<<16, 512, LDS_BYTES, stream>>>(out, w_ih, w_hh, bias,
                                            h0ring, h1ring, out);
  // out = h1 @ w_out^T + b_out (in place)
  proj64<<<(B_ * S_) / 64, 512, 0, stream>>>(out, out, woutbf, b_out);
}

// Round 10
// 7577.877 us; speedup vs baseline: 1.0162x; 1.0162x over previous
//
#include <hip/hip_runtime.h>

// ============================================================================
// 2-layer tanh RNN, B=32, S=2048, D=H=O=512.
//  r9: L0/L1 decoupling on r6's self-tagged MALL rings (no placement tricks).
//   - 16 L0 WGs: ONLY the critical h0 recurrence (Whh0 GEMM, 16 MFMA/wave,
//     1 sync/phase via parity LDS partials, slim finisher).
//   - 16 L1 WGs: 1 phase behind; consume h0 ring + own h1 ring (GEMM1+GEMM2,
//     h1ring + dout stores). h1 loads issued BEFORE the h0 poll, validated
//     after GEMM1 (rare re-poll).
//   - rings depth 8, epoch=(q>>3)&7 tags embedded per-dword (r6 scheme).
//   - flow control: L1 stores progress=p right after its h0(p-1) poll returns;
//     L0 speculatively loads 8 progress lines each phase (drained by its own
//     poll) and spins only if lead > 5 (steady lead 1-2 -> never).
//   - all spins capped -> 'bad' latch (fast fail, never hangs).
// ============================================================================

typedef short v8s __attribute__((ext_vector_type(8)));
typedef int   v4i __attribute__((ext_vector_type(4)));
typedef float v4f __attribute__((ext_vector_type(4)));

#define B_  32
#define S_  2048
#define DH  512
#define RD  8
#define RMASK 7
#define SLOT32 16384                      // u32 per ring slot (32 x 512)
#define EPOCH(q) ((unsigned)(((q) >> 3) & 7))

// ws layout (bytes)
#define PROG_OFF  0                       // [2][8] progress dwords, 256B apart
#define BIAS_OFF  4096                    // [2][512] f32 (b_ih + b_hh)
#define H0_OFF    8192                    // 8 slots x 64KB packed u32
#define H1_OFF    (H0_OFF + 8 * 65536)
#define WOUT_OFF  (H1_OFF + 8 * 65536)    // w_out bf16 [512][512]
#define WIH0_OFF  (WOUT_OFF + 524288)     // w_ih[0] bf16 [512][512]

#define LDS_BYTES (2 * 8 * 2 * 4 * 64 * 16)   // 128KB (L1 worst case)

static __device__ __forceinline__ unsigned short f2bf(float f) {  // RNE
  unsigned int u = __builtin_bit_cast(unsigned int, f);
  u += 0x7fffu + ((u >> 16) & 1u);
  return (unsigned short)(u >> 16);
}
static __device__ __forceinline__ float bf2f(unsigned short h) {
  return __builtin_bit_cast(float, ((unsigned int)h) << 16);
}
static __device__ __forceinline__ unsigned packh(float f, unsigned ep) {
  unsigned short hv = f2bf(f);
  unsigned short lv = f2bf(f - bf2f(hv));
  return ((unsigned)hv << 16) | ((unsigned)lv & 0xFFF8u) | ep;
}
static __device__ __forceinline__ v8s pack8(float4 f0, float4 f1) {
  v8s r;
  r[0] = (short)f2bf(f0.x); r[1] = (short)f2bf(f0.y);
  r[2] = (short)f2bf(f0.z); r[3] = (short)f2bf(f0.w);
  r[4] = (short)f2bf(f1.x); r[5] = (short)f2bf(f1.y);
  r[6] = (short)f2bf(f1.z); r[7] = (short)f2bf(f1.w);
  return r;
}
static __device__ __forceinline__ float fast_tanh(float v) {
  float c = fminf(15.f, fmaxf(-15.f, v));
  float e = __expf(2.f * c);
  return (e - 1.f) * __builtin_amdgcn_rcpf(e + 1.f);
}

// ---- device-scope (MALL) accessors ----------------------------------------
static __device__ __forceinline__ v4i ld16v(const unsigned* p) {
  v4i r;
  asm volatile("global_load_dwordx4 %0, %1, off sc1"
               : "=v"(r) : "v"(p) : "memory");
  return r;
}
static __device__ __forceinline__ float ld4(const void* p) {  // cached
  float r;
  asm volatile("global_load_dword %0, %1, off"
               : "=v"(r) : "v"(p) : "memory");
  return r;
}
static __device__ __forceinline__ unsigned ld4u(const void* p) {  // sc1, unwaited
  unsigned r;
  asm volatile("global_load_dword %0, %1, off sc1"
               : "=v"(r) : "v"(p) : "memory");
  return r;
}
static __device__ __forceinline__ void st32u(void* p, unsigned v) {
  asm volatile("global_store_dword %0, %1, off sc1"
               :: "v"(p), "v"(v) : "memory");
}
static __device__ __forceinline__ void st32m(void* p, unsigned v) {
  asm volatile("global_store_dword %0, %1, off sc0 sc1"
               :: "v"(p), "v"(v) : "memory");
}
static __device__ __forceinline__ int ld_flag(const int* p) {
  int r;
  asm volatile("global_load_dword %0, %1, off sc1\n\ts_waitcnt vmcnt(0)"
               : "=v"(r) : "v"(p) : "memory");
  return r;
}
#define WAITN0() do { asm volatile("s_waitcnt vmcnt(0)" ::: "memory"); \
    __builtin_amdgcn_sched_barrier(0); } while (0)

// Poll one matrix fragment set (16 u32/lane).
static __device__ __forceinline__ void poll_frag(const unsigned* b, unsigned ep,
                                                 bool* bad, v4i* o0, v4i* o1,
                                                 v4i* o2, v4i* o3) {
  v4i a0, a1, a2, a3;
  int t = 0;
  for (;;) {
    a0 = ld16v(b); a1 = ld16v(b + 4); a2 = ld16v(b + 32); a3 = ld16v(b + 36);
    WAITN0();
    if (*bad) break;
    unsigned d = 0;
    #pragma unroll
    for (int j = 0; j < 4; ++j)
      d |= ((unsigned)a0[j] ^ ep) | ((unsigned)a1[j] ^ ep)
         | ((unsigned)a2[j] ^ ep) | ((unsigned)a3[j] ^ ep);
    if (__all((d & 7u) == 0u)) break;
    if (++t > (1 << 15)) { *bad = true; break; }
  }
  *o0 = a0; *o1 = a1; *o2 = a2; *o3 = a3;
}
static __device__ __forceinline__ void unp(v4i a, v4i b, v8s* hi, v8s* lo) {
  v8s h, l;
  #pragma unroll
  for (int j = 0; j < 4; ++j) {
    unsigned ua = (unsigned)a[j], ub = (unsigned)b[j];
    h[j]     = (short)(ua >> 16);   l[j]     = (short)(ua & 0xFFF8u);
    h[4 + j] = (short)(ub >> 16);   l[4 + j] = (short)(ub & 0xFFF8u);
  }
  *hi = h; *lo = l;
}

// ---------------------------------------------------------------------------
__global__ void rnn_init(const float* __restrict__ hidden,
                         const float* __restrict__ b_ih,
                         const float* __restrict__ b_hh,
                         const float* __restrict__ w_out,
                         const float* __restrict__ w_ih,
                         unsigned* __restrict__ progress,
                         float* __restrict__ bias,
                         unsigned* __restrict__ h0ring,
                         unsigned* __restrict__ h1ring,
                         unsigned short* __restrict__ woutbf,
                         unsigned short* __restrict__ wih0bf) {
  int i = blockIdx.x * blockDim.x + threadIdx.x;
  int nth = gridDim.x * blockDim.x;
  for (int t = i; t < 1024; t += nth) st32m(progress + t, 0u);
  for (int t = i; t < 1024; t += nth) bias[t] = b_ih[t] + b_hh[t];
  for (int t = i; t < 2 * B_ * DH; t += nth) {  // initial h -> slot RD-1, tag 7
    int l = t >> 14;
    int off = t & 16383;
    unsigned* ring = l ? h1ring : h0ring;
    st32m(ring + (RD - 1) * SLOT32 + off, packh(hidden[t], 7u));
  }
  for (int t = i; t < 512 * 512; t += nth) {
    woutbf[t] = f2bf(w_out[t]);
    wih0bf[t] = f2bf(w_ih[t]);
  }
}

// ---------------------------------------------------------------------------
// Bulk projection: dst[r][:] = src[r][:] @ wb^T + bias (64 rows/WG, in-place ok)
__global__ __launch_bounds__(512) void proj64(
    const float* __restrict__ src,
    float* __restrict__ dst,
    const unsigned short* __restrict__ wb,
    const float* __restrict__ bias) {
  __shared__ unsigned short lds[64 * 512];
  const int tid = threadIdx.x;
  const int wid = tid >> 6;
  const int lane = tid & 63;
  const size_t row0 = (size_t)blockIdx.x * 64;

  #pragma unroll
  for (int it = 0; it < 8; ++it) {
    int c = it * 512 + tid;
    int row = c >> 6;
    int col8 = c & 63;
    const float4* s4 = (const float4*)(src + (row0 + row) * DH + col8 * 8);
    float4 f0 = s4[0], f1 = s4[1];
    v8s t = pack8(f0, f1);
    int byteoff = row * 1024 + ((col8 * 16) ^ ((row & 7) << 4));
    *(v8s*)((char*)lds + byteoff) = t;
  }
  __syncthreads();

  const int l15 = lane & 15;
  const int kq = (lane >> 4) * 8;

  for (int nt = wid; nt < 32; nt += 8) {
    v4f acc[4];
    #pragma unroll
    for (int mt = 0; mt < 4; ++mt) acc[mt] = (v4f){0.f, 0.f, 0.f, 0.f};
    const unsigned short* wr = wb + (size_t)(nt * 16 + l15) * 512;
    #pragma unroll
    for (int ks = 0; ks < 16; ++ks) {
      int kk = ks * 32 + kq;
      v8s bfrag = *(const v8s*)(wr + kk);
      #pragma unroll
      for (int mt = 0; mt < 4; ++mt) {
        int row = mt * 16 + l15;
        int byteoff = row * 1024 + ((kk * 2) ^ ((row & 7) << 4));
        v8s afrag = *(const v8s*)((char*)lds + byteoff);
        acc[mt] = __builtin_amdgcn_mfma_f32_16x16x32_bf16(afrag, bfrag, acc[mt], 0, 0, 0);
      }
    }
    float bo = bias[nt * 16 + l15];
    #pragma unroll
    for (int mt = 0; mt < 4; ++mt)
      #pragma unroll
      for (int r = 0; r < 4; ++r) {
        int row = mt * 16 + (lane >> 4) * 4 + r;
        int col = nt * 16 + l15;
        dst[(row0 + row) * DH + col] = acc[mt][r] + bo;
      }
  }
}

// ---------------------------------------------------------------------------
// wg 0-15:  L0 (mh=bit3, fs=wg&7) — critical h0 recurrence only.
// wg 16-31: L1 (one phase behind)  — GEMM1+GEMM2, h1 ring, dout, progress.
__global__ __launch_bounds__(512) void rnn_fused(
    const float* __restrict__ z0,
    const float* __restrict__ w_ih,
    const float* __restrict__ w_hh,
    const float* __restrict__ bias,
    unsigned* __restrict__ h0ring,
    unsigned* __restrict__ h1ring,
    unsigned* __restrict__ progress,
    float* __restrict__ dout) {
  extern __shared__ char smem[];
  v4f* part = (v4f*)smem;

  const int wg = blockIdx.x;
  const int role = wg >> 4;
  const int mh = (wg >> 3) & 1;
  const int fs = wg & 7;

  const int tid = threadIdx.x;
  const int wid = tid >> 6;
  const int lane = tid & 63;
  const int l15 = lane & 15;
  const int kq = (lane >> 4) * 8;
  const int q4 = (lane >> 4) * 4;
  const int nf = wid & 3;

  const size_t abase = (size_t)(mh * 16 + l15) * 512 + wid * 64 + kq;
  const int featf = fs * 64 + nf * 16 + l15;
  bool bad = false;

  if (role == 0) {
    // ---- L0: resident Whh0 fragments ------------------------------------
    v8s wf[4][2];
    #pragma unroll
    for (int n = 0; n < 4; ++n)
      #pragma unroll
      for (int ks = 0; ks < 2; ++ks) {
        const float* srow = w_hh +
            (size_t)(fs * 64 + n * 16 + l15) * 512 + wid * 64 + ks * 32 + kq;
        wf[n][ks] = pack8(*(const float4*)srow, *(const float4*)(srow + 4));
      }
    const unsigned* pbase = progress + (size_t)(mh * 8 + (lane & 7)) * 64;

    for (int p = 0; p < S_; ++p) {
      // speculative loads: progress + z0(p) (drained by the h0 poll's wait)
      unsigned prog = ld4u(pbase);
      float zp[4];
      if (wid < 4) {
        #pragma unroll
        for (int r = 0; r < 4; ++r)
          zp[r] = ld4(z0 + ((size_t)(mh * 16 + q4 + r) * S_ + p) * DH + featf);
      }

      const unsigned ep0 = (p == 0) ? 7u : EPOCH(p - 1);
      const unsigned* h0b =
          h0ring + (size_t)((p + RD - 1) & RMASK) * SLOT32 + abase;
      v4i A0, A1, A2, A3;
      poll_frag(h0b, ep0, &bad, &A0, &A1, &A2, &A3);

      asm volatile("" : "+v"(prog));              // value valid only post-wait
      if (p >= 6 && !__all((int)prog >= p - 5)) { // backpressure (rare)
        int t = 0;
        for (;;) {
          int v = ld_flag((const int*)pbase);
          if (__all(v >= p - 5)) break;
          if (++t > (1 << 15)) { bad = true; break; }
        }
      }

      v8s h0, l0, h1f, l1f;
      unp(A0, A1, &h0, &l0);
      unp(A2, A3, &h1f, &l1f);
      #pragma unroll
      for (int n = 0; n < 4; ++n) {
        v4f a = (v4f){0.f, 0.f, 0.f, 0.f};
        a = __builtin_amdgcn_mfma_f32_16x16x32_bf16(h0,  wf[n][0], a, 0, 0, 0);
        a = __builtin_amdgcn_mfma_f32_16x16x32_bf16(l0,  wf[n][0], a, 0, 0, 0);
        a = __builtin_amdgcn_mfma_f32_16x16x32_bf16(h1f, wf[n][1], a, 0, 0, 0);
        a = __builtin_amdgcn_mfma_f32_16x16x32_bf16(l1f, wf[n][1], a, 0, 0, 0);
        part[(((p & 1) * 8 + wid) * 4 + n) * 64 + lane] = a;
      }
      __syncthreads();

      if (wid < 4) {
        v4f s = (v4f){0.f, 0.f, 0.f, 0.f};
        #pragma unroll
        for (int w = 0; w < 8; ++w)
          s += part[(((p & 1) * 8 + w) * 4 + nf) * 64 + lane];
        const unsigned ep = EPOCH(p);
        unsigned* dst = h0ring + (size_t)(p & RMASK) * SLOT32;
        #pragma unroll
        for (int r = 0; r < 4; ++r)
          st32u(dst + (size_t)(mh * 16 + q4 + r) * 512 + featf,
                packh(fast_tanh(zp[r] + s[r]), ep));
      }
    }
  } else {
    // ---- L1: resident Wih1 / Whh1 fragments ------------------------------
    v8s wf[2][4][2];
    {
      const float* wsrcs[2] = { w_ih + 512 * 512, w_hh + 512 * 512 };
      #pragma unroll
      for (int g = 0; g < 2; ++g)
        #pragma unroll
        for (int n = 0; n < 4; ++n)
          #pragma unroll
          for (int ks = 0; ks < 2; ++ks) {
            const float* srow = wsrcs[g] +
                (size_t)(fs * 64 + n * 16 + l15) * 512 + wid * 64 + ks * 32 + kq;
            wf[g][n][ks] = pack8(*(const float4*)srow, *(const float4*)(srow + 4));
          }
    }
    const float bias1v = bias[512 + fs * 64 + nf * 16 + l15];
    unsigned* const myprog = progress + (size_t)(mh * 8 + fs) * 64;

    for (int p = 1; p <= S_; ++p) {
      // early-issue h1(p-2)
      const unsigned ep1 = (p == 1) ? 7u : EPOCH(p - 2);
      const unsigned* h1b =
          h1ring + (size_t)((p + RD - 2) & RMASK) * SLOT32 + abase;
      v4i B0 = ld16v(h1b), B1 = ld16v(h1b + 4);
      v4i B2 = ld16v(h1b + 32), B3 = ld16v(h1b + 36);

      // poll h0(p-1) (its wait also drains B)
      const unsigned* h0b = h0ring + (size_t)((p - 1) & RMASK) * SLOT32 + abase;
      v4i A0, A1, A2, A3;
      poll_frag(h0b, EPOCH(p - 1), &bad, &A0, &A1, &A2, &A3);
      if (tid == 0) st32u(myprog, (unsigned)p);       // done READING h0(p-1)

      v8s ah0, al0, ah1, al1;
      unp(A0, A1, &ah0, &al0);
      unp(A2, A3, &ah1, &al1);
      v4f acc1[4], acc2[4];
      #pragma unroll
      for (int n = 0; n < 4; ++n) {
        acc1[n] = (v4f){0.f, 0.f, 0.f, 0.f};
        acc1[n] = __builtin_amdgcn_mfma_f32_16x16x32_bf16(ah0, wf[0][n][0], acc1[n], 0, 0, 0);
        acc1[n] = __builtin_amdgcn_mfma_f32_16x16x32_bf16(al0, wf[0][n][0], acc1[n], 0, 0, 0);
        acc1[n] = __builtin_amdgcn_mfma_f32_16x16x32_bf16(ah1, wf[0][n][1], acc1[n], 0, 0, 0);
        acc1[n] = __builtin_amdgcn_mfma_f32_16x16x32_bf16(al1, wf[0][n][1], acc1[n], 0, 0, 0);
      }
      {                                               // validate B tags
        unsigned d = 0;
        #pragma unroll
        for (int j = 0; j < 4; ++j)
          d |= ((unsigned)B0[j] ^ ep1) | ((unsigned)B1[j] ^ ep1)
             | ((unsigned)B2[j] ^ ep1) | ((unsigned)B3[j] ^ ep1);
        if (!__all((d & 7u) == 0u))
          poll_frag(h1b, ep1, &bad, &B0, &B1, &B2, &B3);
      }
      v8s bh0, bl0, bh1, bl1;
      unp(B0, B1, &bh0, &bl0);
      unp(B2, B3, &bh1, &bl1);
      #pragma unroll
      for (int n = 0; n < 4; ++n) {
        acc2[n] = (v4f){0.f, 0.f, 0.f, 0.f};
        acc2[n] = __builtin_amdgcn_mfma_f32_16x16x32_bf16(bh0, wf[1][n][0], acc2[n], 0, 0, 0);
        acc2[n] = __builtin_amdgcn_mfma_f32_16x16x32_bf16(bl0, wf[1][n][0], acc2[n], 0, 0, 0);
        acc2[n] = __builtin_amdgcn_mfma_f32_16x16x32_bf16(bh1, wf[1][n][1], acc2[n], 0, 0, 0);
        acc2[n] = __builtin_amdgcn_mfma_f32_16x16x32_bf16(bl1, wf[1][n][1], acc2[n], 0, 0, 0);
      }
      #pragma unroll
      for (int n = 0; n < 4; ++n) {
        part[((((p & 1) * 8 + wid) * 2 + 0) * 4 + n) * 64 + lane] = acc1[n];
        part[((((p & 1) * 8 + wid) * 2 + 1) * 4 + n) * 64 + lane] = acc2[n];
      }
      __syncthreads();

      if (wid < 4) {
        v4f s1 = (v4f){0.f,0.f,0.f,0.f}, s2 = (v4f){0.f,0.f,0.f,0.f};
        #pragma unroll
        for (int w = 0; w < 8; ++w) {
          s1 += part[((((p & 1) * 8 + w) * 2 + 0) * 4 + nf) * 64 + lane];
          s2 += part[((((p & 1) * 8 + w) * 2 + 1) * 4 + nf) * 64 + lane];
        }
        const unsigned ep = EPOCH(p - 1);
        unsigned* dst = h1ring + (size_t)((p - 1) & RMASK) * SLOT32;
        #pragma unroll
        for (int r = 0; r < 4; ++r) {
          float h1v = fast_tanh(s1[r] + s2[r] + bias1v);
          st32u(dst + (size_t)(mh * 16 + q4 + r) * 512 + featf, packh(h1v, ep));
          dout[((size_t)(mh * 16 + q4 + r) * S_ + (p - 1)) * DH + featf] = h1v;
        }
      }
    }
  }
}

// ---------------------------------------------------------------------------
extern "C" void kernel_launch(void* const* d_in, const int* in_sizes, int n_in,
                              void* d_out, int out_size, void* d_ws, size_t ws_size,
                              hipStream_t stream) {
  const float* x      = (const float*)d_in[0];
  const float* hidden = (const float*)d_in[1];
  const float* w_ih   = (const float*)d_in[2];
  const float* w_hh   = (const float*)d_in[3];
  const float* b_ih   = (const float*)d_in[4];
  const float* b_hh   = (const float*)d_in[5];
  const float* w_out  = (const float*)d_in[6];
  const float* b_out  = (const float*)d_in[7];
  float* out = (float*)d_out;

  char* wsb = (char*)d_ws;
  unsigned* progress     = (unsigned*)(wsb + PROG_OFF);
  float* bias            = (float*)(wsb + BIAS_OFF);
  unsigned* h0ring       = (unsigned*)(wsb + H0_OFF);
  unsigned* h1ring       = (unsigned*)(wsb + H1_OFF);
  unsigned short* woutbf = (unsigned short*)(wsb + WOUT_OFF);
  unsigned short* wih0bf = (unsigned short*)(wsb + WIH0_OFF);

  rnn_init<<<256, 256, 0, stream>>>(hidden, b_ih, b_hh, w_out, w_ih,
                                    progress, bias, h0ring, h1ring,
                                    woutbf, wih0bf);
  // Z0 = x @ w_ih0^T + (b_ih0 + b_hh0) -> d_out
  proj64<<<(B_ * S_) / 64, 512, 0, stream>>>(x, out, wih0bf, bias);
  rnn_fused<<<32, 512, LDS_BYTES, stream>>>(out, w_ih, w_hh, bias,
                                            h0ring, h1ring, progress, out);
  // out = h1 @ w_out^T + b_out (in place)
  proj64<<<(B_ * S_) / 64, 512, 0, stream>>>(out, out, woutbf, b_out);
}